// Round 1
// baseline (6446.486 us; speedup 1.0000x reference)
//
#include <hip/hip_runtime.h>

// GCN forward: h1 = A@x ; h2 = relu(h1@W1+b1) ; h3 = A@h2 ; out = h3@W2+b2
// A given as COO edge list (rows, cols, vals), N=100000, E=1.6M, F=H=128, C=64.

// ---------------------------------------------------------------------------
// SpMM scatter: 32 threads per edge, each handles 4 consecutive features.
// out[row][f] += val * x[col][f]   via global fp32 atomics (device scope).
// ---------------------------------------------------------------------------
__global__ __launch_bounds__(256) void spmm_scatter(
    const int* __restrict__ erow, const int* __restrict__ ecol,
    const float* __restrict__ eval, const float* __restrict__ x,
    float* __restrict__ out, int E)
{
    int tid = blockIdx.x * 256 + threadIdx.x;
    int e = tid >> 5;            // 32 threads per edge
    if (e >= E) return;
    int f4 = tid & 31;           // which float4 of the 128-wide feature row
    int r = erow[e];
    int c = ecol[e];
    float v = eval[e];
    float4 xv = ((const float4*)(x + (size_t)c * 128))[f4];
    float* o = out + (size_t)r * 128 + f4 * 4;
    atomicAdd(o + 0, v * xv.x);
    atomicAdd(o + 1, v * xv.y);
    atomicAdd(o + 2, v * xv.z);
    atomicAdd(o + 3, v * xv.w);
}

// ---------------------------------------------------------------------------
// GEMM: out[N,OUT] = (relu?)(A[N,128] @ W[128,OUT] + bias)
// Block = 512 threads. CT = OUT/4 col-threads (each owns 4 output cols),
// RG = 512/CT row-groups, RPT rows per thread, ROWS = RG*RPT rows per block.
// A tile staged in LDS (padded stride 132 -> conflict-free broadcasts),
// W staged in LDS in k-chunks of 32 rows (keeps static LDS < 64 KB).
// ---------------------------------------------------------------------------
template<int OUT, int RPT, bool RELU>
__global__ __launch_bounds__(512) void gemm128(
    const float* __restrict__ A, const float* __restrict__ W,
    const float* __restrict__ bias, float* __restrict__ out, int N)
{
    constexpr int CT   = OUT / 4;     // 32 (OUT=128) or 16 (OUT=64)
    constexpr int RG   = 512 / CT;    // 16 or 32
    constexpr int ROWS = RG * RPT;    // 64 rows per block (both configs)
    constexpr int ALD  = 132;         // padded A leading dim (floats)
    constexpr int KC   = 32;          // k-chunk rows of W staged at a time

    __shared__ float Wl[KC * OUT];    // 16 KB / 8 KB
    __shared__ float Al[ROWS * ALD];  // ~33.8 KB

    const int tid  = threadIdx.x;
    const int j    = tid % CT;        // float4 column index
    const int rg   = tid / CT;        // row group
    const int row0 = blockIdx.x * ROWS;

    // Stage A tile (ROWS x 128) into LDS, float4, zero-padded past N.
    for (int i = tid; i < ROWS * 32; i += 512) {
        int r = i >> 5, kk = i & 31;
        int grow = row0 + r;
        float4 v = make_float4(0.f, 0.f, 0.f, 0.f);
        if (grow < N) v = ((const float4*)(A + (size_t)grow * 128))[kk];
        ((float4*)(Al + r * ALD))[kk] = v;
    }

    float4 acc[RPT];
    float4 bv = ((const float4*)bias)[j];
    #pragma unroll
    for (int r = 0; r < RPT; ++r) acc[r] = bv;

    for (int kc = 0; kc < 128; kc += KC) {
        __syncthreads();  // A tile visible (iter 0); previous W chunk consumed
        for (int i = tid; i < KC * OUT / 4; i += 512)
            ((float4*)Wl)[i] = ((const float4*)W)[kc * CT + i];
        __syncthreads();

        #pragma unroll
        for (int k = 0; k < KC; k += 4) {
            float4 w0 = ((float4*)Wl)[(k + 0) * CT + j];
            float4 w1 = ((float4*)Wl)[(k + 1) * CT + j];
            float4 w2 = ((float4*)Wl)[(k + 2) * CT + j];
            float4 w3 = ((float4*)Wl)[(k + 3) * CT + j];
            #pragma unroll
            for (int r = 0; r < RPT; ++r) {
                const float* ap = Al + (rg * RPT + r) * ALD + kc + k;
                float4 a = *(const float4*)ap;
                acc[r].x = fmaf(a.x, w0.x, acc[r].x);
                acc[r].y = fmaf(a.x, w0.y, acc[r].y);
                acc[r].z = fmaf(a.x, w0.z, acc[r].z);
                acc[r].w = fmaf(a.x, w0.w, acc[r].w);
                acc[r].x = fmaf(a.y, w1.x, acc[r].x);
                acc[r].y = fmaf(a.y, w1.y, acc[r].y);
                acc[r].z = fmaf(a.y, w1.z, acc[r].z);
                acc[r].w = fmaf(a.y, w1.w, acc[r].w);
                acc[r].x = fmaf(a.z, w2.x, acc[r].x);
                acc[r].y = fmaf(a.z, w2.y, acc[r].y);
                acc[r].z = fmaf(a.z, w2.z, acc[r].z);
                acc[r].w = fmaf(a.z, w2.w, acc[r].w);
                acc[r].x = fmaf(a.w, w3.x, acc[r].x);
                acc[r].y = fmaf(a.w, w3.y, acc[r].y);
                acc[r].z = fmaf(a.w, w3.z, acc[r].z);
                acc[r].w = fmaf(a.w, w3.w, acc[r].w);
            }
        }
    }

    #pragma unroll
    for (int r = 0; r < RPT; ++r) {
        int grow = row0 + rg * RPT + r;
        if (grow < N) {
            float4 v = acc[r];
            if (RELU) {
                v.x = fmaxf(v.x, 0.f);
                v.y = fmaxf(v.y, 0.f);
                v.z = fmaxf(v.z, 0.f);
                v.w = fmaxf(v.w, 0.f);
            }
            ((float4*)(out + (size_t)grow * OUT))[j] = v;
        }
    }
}

extern "C" void kernel_launch(void* const* d_in, const int* in_sizes, int n_in,
                              void* d_out, int out_size, void* d_ws, size_t ws_size,
                              hipStream_t stream)
{
    const float* x    = (const float*)d_in[0];
    const int*   erow = (const int*)  d_in[1];
    const int*   ecol = (const int*)  d_in[2];
    const float* eval = (const float*)d_in[3];
    const float* W1   = (const float*)d_in[4];
    const float* b1   = (const float*)d_in[5];
    const float* W2   = (const float*)d_in[6];
    const float* b2   = (const float*)d_in[7];
    float*       out  = (float*)d_out;

    const int N = in_sizes[0] / 128;   // 100000
    const int E = in_sizes[1];         // 1600000

    float* h1 = (float*)d_ws;                       // [N,128] accumulator
    float* h2 = h1 + (size_t)N * 128;               // [N,128] relu output
    const size_t hbytes = (size_t)N * 128 * sizeof(float);

    const int spmm_blocks = (int)(((long long)E * 32 + 255) / 256);
    const int gemm_blocks = (N + 63) / 64;          // 64 rows per block

    // Layer 1: h1 = A @ x ; h2 = relu(h1 @ W1 + b1)
    hipMemsetAsync(h1, 0, hbytes, stream);
    spmm_scatter<<<spmm_blocks, 256, 0, stream>>>(erow, ecol, eval, x, h1, E);
    gemm128<128, 4, true><<<gemm_blocks, 512, 0, stream>>>(h1, W1, b1, h2, N);

    // Layer 2: h1 = A @ h2 ; out = h1 @ W2 + b2
    hipMemsetAsync(h1, 0, hbytes, stream);
    spmm_scatter<<<spmm_blocks, 256, 0, stream>>>(erow, ecol, eval, h2, h1, E);
    gemm128<64, 2, false><<<gemm_blocks, 512, 0, stream>>>(h1, W2, b2, out, N);
}

// Round 2
// 1645.510 us; speedup vs baseline: 3.9176x; 3.9176x over previous
//
#include <hip/hip_runtime.h>

// GCN forward: h1 = A@x ; h2 = relu(h1@W1+b1) ; h3 = A@h2 ; out = h3@W2+b2
// A as COO edge list (rows, cols, vals), N=100000, E=1.6M, F=H=128, C=64.
// Round 2: build CSR on-device (no float atomics), SpMM = row-gather.

// ---------------------------------------------------------------------------
// CSR build step 1: row histogram (int atomics, 1.6M ops over 100k counters)
// ---------------------------------------------------------------------------
__global__ __launch_bounds__(256) void hist_rows(
    const int* __restrict__ erow, int* __restrict__ deg, int E)
{
    int e = blockIdx.x * 256 + threadIdx.x;
    if (e < E) atomicAdd(&deg[erow[e]], 1);
}

// ---------------------------------------------------------------------------
// CSR build step 2: single-block exclusive scan deg[N] -> rp[N+1].
// 1024 threads = 16 waves; wave-level shfl scan + LDS for wave sums.
// ---------------------------------------------------------------------------
__global__ __launch_bounds__(1024) void scan_rowptr(
    const int* __restrict__ deg, int* __restrict__ rp, int N)
{
    __shared__ int wsum[16];
    const int tid  = threadIdx.x;
    const int lane = tid & 63;
    const int wid  = tid >> 6;
    int carry = 0;

    for (int base = 0; base < N; base += 1024) {
        int idx = base + tid;
        int v = (idx < N) ? deg[idx] : 0;
        // inclusive scan within wave
        int sc = v;
        #pragma unroll
        for (int d = 1; d < 64; d <<= 1) {
            int t = __shfl_up(sc, d);
            if (lane >= d) sc += t;
        }
        if (lane == 63) wsum[wid] = sc;
        __syncthreads();
        if (wid == 0) {
            int ws = (lane < 16) ? wsum[lane] : 0;
            #pragma unroll
            for (int d = 1; d < 16; d <<= 1) {
                int t = __shfl_up(ws, d);
                if (lane >= d) ws += t;
            }
            if (lane < 16) wsum[lane] = ws;   // inclusive wave-sum scan
        }
        __syncthreads();
        int woff = (wid == 0) ? 0 : wsum[wid - 1];
        if (idx < N) rp[idx] = carry + woff + sc - v;   // exclusive
        carry += wsum[15];
        __syncthreads();   // protect wsum before next chunk overwrites
    }
    if (tid == 0) rp[N] = carry;
}

// ---------------------------------------------------------------------------
// CSR build step 3: bucket fill. cursor starts as a copy of rp.
// ---------------------------------------------------------------------------
__global__ __launch_bounds__(256) void fill_csr(
    const int* __restrict__ erow, const int* __restrict__ ecol,
    const float* __restrict__ eval, int* __restrict__ cursor,
    int* __restrict__ ccol, float* __restrict__ cval, int E)
{
    int e = blockIdx.x * 256 + threadIdx.x;
    if (e < E) {
        int r = erow[e];
        int p = atomicAdd(&cursor[r], 1);
        ccol[p] = ecol[e];
        cval[p] = eval[e];
    }
}

// ---------------------------------------------------------------------------
// SpMM (CSR): one wave per row, lane owns a float2 feature chunk (64*2=128).
// 2-edge unrolled loop for memory-level parallelism. Coalesced row write.
// ---------------------------------------------------------------------------
__global__ __launch_bounds__(256) void spmm_csr(
    const int* __restrict__ rp, const int* __restrict__ ccol,
    const float* __restrict__ cval, const float* __restrict__ x,
    float* __restrict__ out, int N)
{
    int row = (blockIdx.x * 256 + threadIdx.x) >> 6;
    if (row >= N) return;
    int lane = threadIdx.x & 63;
    const float2* xf = (const float2*)x;

    int s = rp[row], e = rp[row + 1];
    float2 a0 = make_float2(0.f, 0.f);
    float2 a1 = make_float2(0.f, 0.f);
    int i = s;
    for (; i + 1 < e; i += 2) {
        int   c0 = ccol[i],  c1 = ccol[i + 1];
        float v0 = cval[i],  v1 = cval[i + 1];
        float2 x0 = xf[(size_t)c0 * 64 + lane];
        float2 x1 = xf[(size_t)c1 * 64 + lane];
        a0.x = fmaf(v0, x0.x, a0.x);  a0.y = fmaf(v0, x0.y, a0.y);
        a1.x = fmaf(v1, x1.x, a1.x);  a1.y = fmaf(v1, x1.y, a1.y);
    }
    if (i < e) {
        int   c0 = ccol[i];
        float v0 = cval[i];
        float2 x0 = xf[(size_t)c0 * 64 + lane];
        a0.x = fmaf(v0, x0.x, a0.x);  a0.y = fmaf(v0, x0.y, a0.y);
    }
    ((float2*)out)[(size_t)row * 64 + lane] =
        make_float2(a0.x + a1.x, a0.y + a1.y);
}

// ---------------------------------------------------------------------------
// GEMM: out[N,OUT] = (relu?)(A[N,128] @ W[128,OUT] + bias)   (unchanged)
// ---------------------------------------------------------------------------
template<int OUT, int RPT, bool RELU>
__global__ __launch_bounds__(512) void gemm128(
    const float* __restrict__ A, const float* __restrict__ W,
    const float* __restrict__ bias, float* __restrict__ out, int N)
{
    constexpr int CT   = OUT / 4;
    constexpr int RG   = 512 / CT;
    constexpr int ROWS = RG * RPT;
    constexpr int ALD  = 132;
    constexpr int KC   = 32;

    __shared__ float Wl[KC * OUT];
    __shared__ float Al[ROWS * ALD];

    const int tid  = threadIdx.x;
    const int j    = tid % CT;
    const int rg   = tid / CT;
    const int row0 = blockIdx.x * ROWS;

    for (int i = tid; i < ROWS * 32; i += 512) {
        int r = i >> 5, kk = i & 31;
        int grow = row0 + r;
        float4 v = make_float4(0.f, 0.f, 0.f, 0.f);
        if (grow < N) v = ((const float4*)(A + (size_t)grow * 128))[kk];
        ((float4*)(Al + r * ALD))[kk] = v;
    }

    float4 acc[RPT];
    float4 bv = ((const float4*)bias)[j];
    #pragma unroll
    for (int r = 0; r < RPT; ++r) acc[r] = bv;

    for (int kc = 0; kc < 128; kc += KC) {
        __syncthreads();
        for (int i = tid; i < KC * OUT / 4; i += 512)
            ((float4*)Wl)[i] = ((const float4*)W)[kc * CT + i];
        __syncthreads();

        #pragma unroll
        for (int k = 0; k < KC; k += 4) {
            float4 w0 = ((float4*)Wl)[(k + 0) * CT + j];
            float4 w1 = ((float4*)Wl)[(k + 1) * CT + j];
            float4 w2 = ((float4*)Wl)[(k + 2) * CT + j];
            float4 w3 = ((float4*)Wl)[(k + 3) * CT + j];
            #pragma unroll
            for (int r = 0; r < RPT; ++r) {
                const float* ap = Al + (rg * RPT + r) * ALD + kc + k;
                float4 a = *(const float4*)ap;
                acc[r].x = fmaf(a.x, w0.x, acc[r].x);
                acc[r].y = fmaf(a.x, w0.y, acc[r].y);
                acc[r].z = fmaf(a.x, w0.z, acc[r].z);
                acc[r].w = fmaf(a.x, w0.w, acc[r].w);
                acc[r].x = fmaf(a.y, w1.x, acc[r].x);
                acc[r].y = fmaf(a.y, w1.y, acc[r].y);
                acc[r].z = fmaf(a.y, w1.z, acc[r].z);
                acc[r].w = fmaf(a.y, w1.w, acc[r].w);
                acc[r].x = fmaf(a.z, w2.x, acc[r].x);
                acc[r].y = fmaf(a.z, w2.y, acc[r].y);
                acc[r].z = fmaf(a.z, w2.z, acc[r].z);
                acc[r].w = fmaf(a.z, w2.w, acc[r].w);
                acc[r].x = fmaf(a.w, w3.x, acc[r].x);
                acc[r].y = fmaf(a.w, w3.y, acc[r].y);
                acc[r].z = fmaf(a.w, w3.z, acc[r].z);
                acc[r].w = fmaf(a.w, w3.w, acc[r].w);
            }
        }
    }

    #pragma unroll
    for (int r = 0; r < RPT; ++r) {
        int grow = row0 + rg * RPT + r;
        if (grow < N) {
            float4 v = acc[r];
            if (RELU) {
                v.x = fmaxf(v.x, 0.f);
                v.y = fmaxf(v.y, 0.f);
                v.z = fmaxf(v.z, 0.f);
                v.w = fmaxf(v.w, 0.f);
            }
            ((float4*)(out + (size_t)grow * OUT))[j] = v;
        }
    }
}

extern "C" void kernel_launch(void* const* d_in, const int* in_sizes, int n_in,
                              void* d_out, int out_size, void* d_ws, size_t ws_size,
                              hipStream_t stream)
{
    const float* x    = (const float*)d_in[0];
    const int*   erow = (const int*)  d_in[1];
    const int*   ecol = (const int*)  d_in[2];
    const float* eval = (const float*)d_in[3];
    const float* W1   = (const float*)d_in[4];
    const float* b1   = (const float*)d_in[5];
    const float* W2   = (const float*)d_in[6];
    const float* b2   = (const float*)d_in[7];
    float*       out  = (float*)d_out;

    const int N = in_sizes[0] / 128;   // 100000
    const int E = in_sizes[1];         // 1600000

    // Workspace layout (floats first, then ints): ~116 MB total
    float* h1     = (float*)d_ws;                     // [N,128]
    float* h2     = h1 + (size_t)N * 128;             // [N,128]
    float* cval   = h2 + (size_t)N * 128;             // [E]
    int*   ccol   = (int*)(cval + E);                 // [E]
    int*   rp     = ccol + E;                         // [N+1]
    int*   cursor = rp + (N + 1);                     // [N] (also deg)

    const int eblocks = (E + 255) / 256;
    const int spmm_blocks = (N + 3) / 4;              // 4 rows (waves) / block
    const int gemm_blocks = (N + 63) / 64;

    // ---- Build CSR (once; reused by both layers) ----
    hipMemsetAsync(cursor, 0, (size_t)N * sizeof(int), stream);   // deg = 0
    hist_rows<<<eblocks, 256, 0, stream>>>(erow, cursor, E);
    scan_rowptr<<<1, 1024, 0, stream>>>(cursor, rp, N);
    hipMemcpyAsync(cursor, rp, (size_t)N * sizeof(int),
                   hipMemcpyDeviceToDevice, stream);
    fill_csr<<<eblocks, 256, 0, stream>>>(erow, ecol, eval, cursor,
                                          ccol, cval, E);

    // ---- Layer 1 ----
    spmm_csr<<<spmm_blocks, 256, 0, stream>>>(rp, ccol, cval, x, h1, N);
    gemm128<128, 4, true><<<gemm_blocks, 512, 0, stream>>>(h1, W1, b1, h2, N);

    // ---- Layer 2 ----
    spmm_csr<<<spmm_blocks, 256, 0, stream>>>(rp, ccol, cval, h2, h1, N);
    gemm128<64, 2, false><<<gemm_blocks, 512, 0, stream>>>(h1, W2, b2, out, N);
}

// Round 3
// 1580.361 us; speedup vs baseline: 4.0791x; 1.0412x over previous
//
#include <hip/hip_runtime.h>

// GCN forward, reassociated:
//   y1 = x @ W1            (dense GEMM, N x 128 x 128)
//   h2 = relu(A @ y1 + b1) (SpMM 128-wide, fused bias+relu)
//   y2 = h2 @ W2           (dense GEMM, N x 128 x 64)
//   out = A @ y2 + b2      (SpMM 64-wide, fused bias)
// A as COO edges -> CSR built on device once per call.

// ---------------------------------------------------------------------------
// CSR build step 1: row histogram
// ---------------------------------------------------------------------------
__global__ __launch_bounds__(256) void hist_rows(
    const int* __restrict__ erow, int* __restrict__ deg, int E)
{
    int e = blockIdx.x * 256 + threadIdx.x;
    if (e < E) atomicAdd(&deg[erow[e]], 1);
}

// ---------------------------------------------------------------------------
// CSR build step 2: single-block exclusive scan deg[N] -> rp[N+1]
// ---------------------------------------------------------------------------
__global__ __launch_bounds__(1024) void scan_rowptr(
    const int* __restrict__ deg, int* __restrict__ rp, int N)
{
    __shared__ int wsum[16];
    const int tid  = threadIdx.x;
    const int lane = tid & 63;
    const int wid  = tid >> 6;
    int carry = 0;

    for (int base = 0; base < N; base += 1024) {
        int idx = base + tid;
        int v = (idx < N) ? deg[idx] : 0;
        int sc = v;
        #pragma unroll
        for (int d = 1; d < 64; d <<= 1) {
            int t = __shfl_up(sc, d);
            if (lane >= d) sc += t;
        }
        if (lane == 63) wsum[wid] = sc;
        __syncthreads();
        if (wid == 0) {
            int ws = (lane < 16) ? wsum[lane] : 0;
            #pragma unroll
            for (int d = 1; d < 16; d <<= 1) {
                int t = __shfl_up(ws, d);
                if (lane >= d) ws += t;
            }
            if (lane < 16) wsum[lane] = ws;
        }
        __syncthreads();
        int woff = (wid == 0) ? 0 : wsum[wid - 1];
        if (idx < N) rp[idx] = carry + woff + sc - v;
        carry += wsum[15];
        __syncthreads();
    }
    if (tid == 0) rp[N] = carry;
}

// ---------------------------------------------------------------------------
// CSR build step 3: bucket fill (cursor starts as copy of rp)
// ---------------------------------------------------------------------------
__global__ __launch_bounds__(256) void fill_csr(
    const int* __restrict__ erow, const int* __restrict__ ecol,
    const float* __restrict__ eval, int* __restrict__ cursor,
    int* __restrict__ ccol, float* __restrict__ cval, int E)
{
    int e = blockIdx.x * 256 + threadIdx.x;
    if (e < E) {
        int r = erow[e];
        int p = atomicAdd(&cursor[r], 1);
        ccol[p] = ecol[e];
        cval[p] = eval[e];
    }
}

// ---------------------------------------------------------------------------
// SpMM 128-wide (CSR): one wave per row, lane owns float2 (64*2=128 feats).
// 4-edge unroll for MLP. Fused bias (+optional relu) epilogue.
// ---------------------------------------------------------------------------
template<bool RELU>
__global__ __launch_bounds__(256) void spmm128(
    const int* __restrict__ rp, const int* __restrict__ ccol,
    const float* __restrict__ cval, const float* __restrict__ x,
    const float* __restrict__ bias, float* __restrict__ out, int N)
{
    int row = (blockIdx.x * 256 + threadIdx.x) >> 6;
    if (row >= N) return;
    int lane = threadIdx.x & 63;
    const float2* xf = (const float2*)x;

    int s = rp[row], e = rp[row + 1];
    float2 a0 = make_float2(0.f, 0.f);
    float2 a1 = make_float2(0.f, 0.f);
    float2 a2 = make_float2(0.f, 0.f);
    float2 a3 = make_float2(0.f, 0.f);
    int i = s;
    for (; i + 3 < e; i += 4) {
        int   c0 = ccol[i],     c1 = ccol[i + 1];
        int   c2 = ccol[i + 2], c3 = ccol[i + 3];
        float v0 = cval[i],     v1 = cval[i + 1];
        float v2 = cval[i + 2], v3 = cval[i + 3];
        float2 x0 = xf[(size_t)c0 * 64 + lane];
        float2 x1 = xf[(size_t)c1 * 64 + lane];
        float2 x2 = xf[(size_t)c2 * 64 + lane];
        float2 x3 = xf[(size_t)c3 * 64 + lane];
        a0.x = fmaf(v0, x0.x, a0.x);  a0.y = fmaf(v0, x0.y, a0.y);
        a1.x = fmaf(v1, x1.x, a1.x);  a1.y = fmaf(v1, x1.y, a1.y);
        a2.x = fmaf(v2, x2.x, a2.x);  a2.y = fmaf(v2, x2.y, a2.y);
        a3.x = fmaf(v3, x3.x, a3.x);  a3.y = fmaf(v3, x3.y, a3.y);
    }
    for (; i < e; ++i) {
        int   c0 = ccol[i];
        float v0 = cval[i];
        float2 x0 = xf[(size_t)c0 * 64 + lane];
        a0.x = fmaf(v0, x0.x, a0.x);  a0.y = fmaf(v0, x0.y, a0.y);
    }
    float2 b = ((const float2*)bias)[lane];
    float rx = a0.x + a1.x + a2.x + a3.x + b.x;
    float ry = a0.y + a1.y + a2.y + a3.y + b.y;
    if (RELU) { rx = fmaxf(rx, 0.f); ry = fmaxf(ry, 0.f); }
    ((float2*)out)[(size_t)row * 64 + lane] = make_float2(rx, ry);
}

// ---------------------------------------------------------------------------
// SpMM 64-wide (CSR): one wave per row; half-waves take alternating edges
// (lane 0-31 even, 32-63 odd), each half reads its edge's full 256 B row as
// float2 per lane. Combine halves with shfl_xor(32). Fused bias epilogue.
// ---------------------------------------------------------------------------
__global__ __launch_bounds__(256) void spmm64_bias(
    const int* __restrict__ rp, const int* __restrict__ ccol,
    const float* __restrict__ cval, const float* __restrict__ x,
    const float* __restrict__ bias, float* __restrict__ out, int N)
{
    int row = (blockIdx.x * 256 + threadIdx.x) >> 6;
    if (row >= N) return;
    int lane = threadIdx.x & 63;
    int half = lane >> 5;
    int fl   = lane & 31;            // float2 chunk over 64 feats
    const float2* xf = (const float2*)x;

    int s = rp[row], e = rp[row + 1];
    float2 a0 = make_float2(0.f, 0.f);
    float2 a1 = make_float2(0.f, 0.f);
    int i = s + half;
    for (; i + 2 < e; i += 4) {      // this half handles i and i+2
        int   c0 = ccol[i],  c1 = ccol[i + 2];
        float v0 = cval[i],  v1 = cval[i + 2];
        float2 x0 = xf[(size_t)c0 * 32 + fl];
        float2 x1 = xf[(size_t)c1 * 32 + fl];
        a0.x = fmaf(v0, x0.x, a0.x);  a0.y = fmaf(v0, x0.y, a0.y);
        a1.x = fmaf(v1, x1.x, a1.x);  a1.y = fmaf(v1, x1.y, a1.y);
    }
    if (i < e) {
        int   c0 = ccol[i];
        float v0 = cval[i];
        float2 x0 = xf[(size_t)c0 * 32 + fl];
        a0.x = fmaf(v0, x0.x, a0.x);  a0.y = fmaf(v0, x0.y, a0.y);
    }
    float rx = a0.x + a1.x;
    float ry = a0.y + a1.y;
    rx += __shfl_xor(rx, 32);
    ry += __shfl_xor(ry, 32);
    if (half == 0) {
        float2 b = ((const float2*)bias)[fl];
        ((float2*)out)[(size_t)row * 32 + fl] = make_float2(rx + b.x, ry + b.y);
    }
}

// ---------------------------------------------------------------------------
// GEMM: out[N,OUT] = A[N,128] @ W[128,OUT]   (no bias / activation)
// ---------------------------------------------------------------------------
template<int OUT, int RPT>
__global__ __launch_bounds__(512) void gemm128(
    const float* __restrict__ A, const float* __restrict__ W,
    float* __restrict__ out, int N)
{
    constexpr int CT   = OUT / 4;
    constexpr int RG   = 512 / CT;
    constexpr int ROWS = RG * RPT;
    constexpr int ALD  = 132;
    constexpr int KC   = 32;

    __shared__ float Wl[KC * OUT];
    __shared__ float Al[ROWS * ALD];

    const int tid  = threadIdx.x;
    const int j    = tid % CT;
    const int rg   = tid / CT;
    const int row0 = blockIdx.x * ROWS;

    for (int i = tid; i < ROWS * 32; i += 512) {
        int r = i >> 5, kk = i & 31;
        int grow = row0 + r;
        float4 v = make_float4(0.f, 0.f, 0.f, 0.f);
        if (grow < N) v = ((const float4*)(A + (size_t)grow * 128))[kk];
        ((float4*)(Al + r * ALD))[kk] = v;
    }

    float4 acc[RPT];
    #pragma unroll
    for (int r = 0; r < RPT; ++r) acc[r] = make_float4(0.f, 0.f, 0.f, 0.f);

    for (int kc = 0; kc < 128; kc += KC) {
        __syncthreads();
        for (int i = tid; i < KC * OUT / 4; i += 512)
            ((float4*)Wl)[i] = ((const float4*)W)[kc * CT + i];
        __syncthreads();

        #pragma unroll
        for (int k = 0; k < KC; k += 4) {
            float4 w0 = ((float4*)Wl)[(k + 0) * CT + j];
            float4 w1 = ((float4*)Wl)[(k + 1) * CT + j];
            float4 w2 = ((float4*)Wl)[(k + 2) * CT + j];
            float4 w3 = ((float4*)Wl)[(k + 3) * CT + j];
            #pragma unroll
            for (int r = 0; r < RPT; ++r) {
                const float* ap = Al + (rg * RPT + r) * ALD + kc + k;
                float4 a = *(const float4*)ap;
                acc[r].x = fmaf(a.x, w0.x, acc[r].x);
                acc[r].y = fmaf(a.x, w0.y, acc[r].y);
                acc[r].z = fmaf(a.x, w0.z, acc[r].z);
                acc[r].w = fmaf(a.x, w0.w, acc[r].w);
                acc[r].x = fmaf(a.y, w1.x, acc[r].x);
                acc[r].y = fmaf(a.y, w1.y, acc[r].y);
                acc[r].z = fmaf(a.y, w1.z, acc[r].z);
                acc[r].w = fmaf(a.y, w1.w, acc[r].w);
                acc[r].x = fmaf(a.z, w2.x, acc[r].x);
                acc[r].y = fmaf(a.z, w2.y, acc[r].y);
                acc[r].z = fmaf(a.z, w2.z, acc[r].z);
                acc[r].w = fmaf(a.z, w2.w, acc[r].w);
                acc[r].x = fmaf(a.w, w3.x, acc[r].x);
                acc[r].y = fmaf(a.w, w3.y, acc[r].y);
                acc[r].z = fmaf(a.w, w3.z, acc[r].z);
                acc[r].w = fmaf(a.w, w3.w, acc[r].w);
            }
        }
    }

    #pragma unroll
    for (int r = 0; r < RPT; ++r) {
        int grow = row0 + rg * RPT + r;
        if (grow < N)
            ((float4*)(out + (size_t)grow * OUT))[j] = acc[r];
    }
}

extern "C" void kernel_launch(void* const* d_in, const int* in_sizes, int n_in,
                              void* d_out, int out_size, void* d_ws, size_t ws_size,
                              hipStream_t stream)
{
    const float* x    = (const float*)d_in[0];
    const int*   erow = (const int*)  d_in[1];
    const int*   ecol = (const int*)  d_in[2];
    const float* eval = (const float*)d_in[3];
    const float* W1   = (const float*)d_in[4];
    const float* b1   = (const float*)d_in[5];
    const float* W2   = (const float*)d_in[6];
    const float* b2   = (const float*)d_in[7];
    float*       out  = (float*)d_out;

    const int N = in_sizes[0] / 128;   // 100000
    const int E = in_sizes[1];         // 1600000

    // Workspace: y1 [N,128] (reused as y2 [N,64]), h2 [N,128], cval [E],
    // ccol [E], rp [N+1], cursor/deg [N]  -> same footprint as round 2.
    float* y1     = (float*)d_ws;
    float* h2     = y1 + (size_t)N * 128;
    float* cval   = h2 + (size_t)N * 128;
    int*   ccol   = (int*)(cval + E);
    int*   rp     = ccol + E;
    int*   cursor = rp + (N + 1);
    float* y2     = y1;                 // y1 dead once h2 exists

    const int eblocks     = (E + 255) / 256;
    const int spmm_blocks = (N + 3) / 4;
    const int gemm_blocks = (N + 63) / 64;

    // ---- Build CSR ----
    hipMemsetAsync(cursor, 0, (size_t)N * sizeof(int), stream);
    hist_rows<<<eblocks, 256, 0, stream>>>(erow, cursor, E);
    scan_rowptr<<<1, 1024, 0, stream>>>(cursor, rp, N);
    hipMemcpyAsync(cursor, rp, (size_t)N * sizeof(int),
                   hipMemcpyDeviceToDevice, stream);
    fill_csr<<<eblocks, 256, 0, stream>>>(erow, ecol, eval, cursor,
                                          ccol, cval, E);

    // ---- Layer 1 (reassociated): y1 = x@W1 ; h2 = relu(A@y1 + b1) ----
    gemm128<128, 4><<<gemm_blocks, 512, 0, stream>>>(x, W1, y1, N);
    spmm128<true><<<spmm_blocks, 256, 0, stream>>>(rp, ccol, cval, y1, b1, h2, N);

    // ---- Layer 2 (reassociated): y2 = h2@W2 ; out = A@y2 + b2 ----
    gemm128<64, 2><<<gemm_blocks, 512, 0, stream>>>(h2, W2, y2, N);
    spmm64_bias<<<spmm_blocks, 256, 0, stream>>>(rp, ccol, cval, y2, b2, out, N);
}

// Round 4
// 575.508 us; speedup vs baseline: 11.2014x; 2.7460x over previous
//
#include <hip/hip_runtime.h>

// GCN forward, reassociated + bf16 tables + MFMA GEMMs:
//   y1b = bf16(x @ W1)             (MFMA bf16 GEMM, N x 128 x 128)
//   h2b = bf16(relu(A @ y1b + b1)) (SpMM 128-wide gather, bf16 table)
//   y2b = bf16(h2b @ W2)           (MFMA bf16 GEMM, N x 128 x 64)
//   out = A @ y2b + b2             (SpMM 64-wide gather, fp32 out)
// A as COO edges -> CSR built on device once per call.

typedef __attribute__((ext_vector_type(8))) short short8;
typedef __attribute__((ext_vector_type(4))) float floatx4;

static __device__ __forceinline__ unsigned short f2bf(float f) {
    unsigned int u = __builtin_bit_cast(unsigned int, f);
    u += 0x7fffu + ((u >> 16) & 1u);        // round-to-nearest-even
    return (unsigned short)(u >> 16);
}
static __device__ __forceinline__ float bflo(unsigned int u) {
    return __builtin_bit_cast(float, u << 16);
}
static __device__ __forceinline__ float bfhi(unsigned int u) {
    return __builtin_bit_cast(float, u & 0xffff0000u);
}

// ---------------------------------------------------------------------------
// CSR build step 1: row histogram
// ---------------------------------------------------------------------------
__global__ __launch_bounds__(256) void hist_rows(
    const int* __restrict__ erow, int* __restrict__ deg, int E)
{
    int e = blockIdx.x * 256 + threadIdx.x;
    if (e < E) atomicAdd(&deg[erow[e]], 1);
}

// ---------------------------------------------------------------------------
// CSR build step 2: single-block exclusive scan deg[N] -> rp[N+1]
// ---------------------------------------------------------------------------
__global__ __launch_bounds__(1024) void scan_rowptr(
    const int* __restrict__ deg, int* __restrict__ rp, int N)
{
    __shared__ int wsum[16];
    const int tid  = threadIdx.x;
    const int lane = tid & 63;
    const int wid  = tid >> 6;
    int carry = 0;

    for (int base = 0; base < N; base += 1024) {
        int idx = base + tid;
        int v = (idx < N) ? deg[idx] : 0;
        int sc = v;
        #pragma unroll
        for (int d = 1; d < 64; d <<= 1) {
            int t = __shfl_up(sc, d);
            if (lane >= d) sc += t;
        }
        if (lane == 63) wsum[wid] = sc;
        __syncthreads();
        if (wid == 0) {
            int ws = (lane < 16) ? wsum[lane] : 0;
            #pragma unroll
            for (int d = 1; d < 16; d <<= 1) {
                int t = __shfl_up(ws, d);
                if (lane >= d) ws += t;
            }
            if (lane < 16) wsum[lane] = ws;
        }
        __syncthreads();
        int woff = (wid == 0) ? 0 : wsum[wid - 1];
        if (idx < N) rp[idx] = carry + woff + sc - v;
        carry += wsum[15];
        __syncthreads();
    }
    if (tid == 0) rp[N] = carry;
}

// ---------------------------------------------------------------------------
// CSR build step 3: bucket fill (cursor starts as copy of rp)
// ---------------------------------------------------------------------------
__global__ __launch_bounds__(256) void fill_csr(
    const int* __restrict__ erow, const int* __restrict__ ecol,
    const float* __restrict__ eval, int* __restrict__ cursor,
    int* __restrict__ ccol, float* __restrict__ cval, int E)
{
    int e = blockIdx.x * 256 + threadIdx.x;
    if (e < E) {
        int r = erow[e];
        int p = atomicAdd(&cursor[r], 1);
        ccol[p] = ecol[e];
        cval[p] = eval[e];
    }
}

// ---------------------------------------------------------------------------
// W cast+transpose: W[K][OUT] fp32 -> Wt[OUT][K] bf16 (tiny, once per call)
// ---------------------------------------------------------------------------
__global__ __launch_bounds__(256) void cast_transpose_w(
    const float* __restrict__ W, unsigned short* __restrict__ Wt,
    int K, int OUT)
{
    int idx = blockIdx.x * 256 + threadIdx.x;
    if (idx < K * OUT) {
        int n = idx / K, k = idx - n * K;
        Wt[idx] = f2bf(W[(size_t)k * OUT + n]);
    }
}

// ---------------------------------------------------------------------------
// MFMA GEMM: Y[N,OUT] = bf16(A[N,128] @ W[128,OUT]), Wt is [OUT][128] bf16.
// Block = 256 (4 waves); wave computes 16 rows x OUT cols via 16x16x32 MFMA.
// Verified gfx950 layouts: A/B frag [lane&15][quad*8+j]; C/D col=lane&15,
// row=quad*4+reg.
// ---------------------------------------------------------------------------
template<int OUT, bool AF32>
static __device__ __forceinline__ void gemm_mfma_body(
    const void* __restrict__ Av, const unsigned short* __restrict__ Wt,
    unsigned short* __restrict__ Y, int N)
{
    constexpr int NT = OUT / 16;
    const int lane = threadIdx.x & 63;
    const int wave = threadIdx.x >> 6;
    const int quad = lane >> 4;
    const int l16  = lane & 15;
    const int row0 = blockIdx.x * 64 + wave * 16;
    int arow = row0 + l16;
    if (arow > N - 1) arow = N - 1;      // clamp: stores are guarded below

    short8 af[4];
    if (AF32) {
        const float* ap = (const float*)Av + (size_t)arow * 128 + quad * 8;
        #pragma unroll
        for (int kt = 0; kt < 4; ++kt) {
            const float4* p = (const float4*)(ap + kt * 32);
            float4 lo = p[0], hi = p[1];
            short8 t;
            t[0] = (short)f2bf(lo.x); t[1] = (short)f2bf(lo.y);
            t[2] = (short)f2bf(lo.z); t[3] = (short)f2bf(lo.w);
            t[4] = (short)f2bf(hi.x); t[5] = (short)f2bf(hi.y);
            t[6] = (short)f2bf(hi.z); t[7] = (short)f2bf(hi.w);
            af[kt] = t;
        }
    } else {
        const unsigned short* ap =
            (const unsigned short*)Av + (size_t)arow * 128 + quad * 8;
        #pragma unroll
        for (int kt = 0; kt < 4; ++kt)
            af[kt] = *(const short8*)(ap + kt * 32);
    }

    floatx4 acc[NT];
    #pragma unroll
    for (int nt = 0; nt < NT; ++nt) acc[nt] = (floatx4){0.f, 0.f, 0.f, 0.f};

    #pragma unroll
    for (int nt = 0; nt < NT; ++nt) {
        const unsigned short* wp = Wt + (size_t)(nt * 16 + l16) * 128 + quad * 8;
        #pragma unroll
        for (int kt = 0; kt < 4; ++kt) {
            short8 bfr = *(const short8*)(wp + kt * 32);
            acc[nt] = __builtin_amdgcn_mfma_f32_16x16x32_bf16(
                af[kt], bfr, acc[nt], 0, 0, 0);
        }
    }

    #pragma unroll
    for (int nt = 0; nt < NT; ++nt) {
        int col = nt * 16 + l16;
        #pragma unroll
        for (int r = 0; r < 4; ++r) {
            int row = row0 + quad * 4 + r;
            if (row < N)
                Y[(size_t)row * OUT + col] = f2bf(acc[nt][r]);
        }
    }
}

__global__ __launch_bounds__(256) void gemm1_mfma(
    const float* __restrict__ A, const unsigned short* __restrict__ Wt,
    unsigned short* __restrict__ Y, int N)
{
    gemm_mfma_body<128, true>(A, Wt, Y, N);
}

__global__ __launch_bounds__(256) void gemm2_mfma(
    const unsigned short* __restrict__ A, const unsigned short* __restrict__ Wt,
    unsigned short* __restrict__ Y, int N)
{
    gemm_mfma_body<64, false>(A, Wt, Y, N);
}

// ---------------------------------------------------------------------------
// SpMM 128-wide (CSR, bf16 table): wave per row, lane owns 2 feats (1 uint).
// 4-edge unroll; fused bias+relu; bf16 output.
// ---------------------------------------------------------------------------
template<bool RELU>
__global__ __launch_bounds__(256) void spmm_gather128(
    const int* __restrict__ rp, const int* __restrict__ ccol,
    const float* __restrict__ cval, const unsigned short* __restrict__ xb,
    const float* __restrict__ bias, unsigned short* __restrict__ outb, int N)
{
    int row = (blockIdx.x * 256 + threadIdx.x) >> 6;
    if (row >= N) return;
    int lane = threadIdx.x & 63;
    const unsigned int* xf = (const unsigned int*)xb;

    int s = rp[row], e = rp[row + 1];
    float x0 = 0.f, y0 = 0.f, x1 = 0.f, y1 = 0.f;
    float x2 = 0.f, y2 = 0.f, x3 = 0.f, y3 = 0.f;
    int i = s;
    for (; i + 3 < e; i += 4) {
        int   c0 = ccol[i],     c1 = ccol[i + 1];
        int   c2 = ccol[i + 2], c3 = ccol[i + 3];
        float v0 = cval[i],     v1 = cval[i + 1];
        float v2 = cval[i + 2], v3 = cval[i + 3];
        unsigned int u0 = xf[(size_t)c0 * 64 + lane];
        unsigned int u1 = xf[(size_t)c1 * 64 + lane];
        unsigned int u2 = xf[(size_t)c2 * 64 + lane];
        unsigned int u3 = xf[(size_t)c3 * 64 + lane];
        x0 = fmaf(v0, bflo(u0), x0);  y0 = fmaf(v0, bfhi(u0), y0);
        x1 = fmaf(v1, bflo(u1), x1);  y1 = fmaf(v1, bfhi(u1), y1);
        x2 = fmaf(v2, bflo(u2), x2);  y2 = fmaf(v2, bfhi(u2), y2);
        x3 = fmaf(v3, bflo(u3), x3);  y3 = fmaf(v3, bfhi(u3), y3);
    }
    for (; i < e; ++i) {
        int c0 = ccol[i]; float v0 = cval[i];
        unsigned int u0 = xf[(size_t)c0 * 64 + lane];
        x0 = fmaf(v0, bflo(u0), x0);  y0 = fmaf(v0, bfhi(u0), y0);
    }
    float2 b = ((const float2*)bias)[lane];
    float sx = x0 + x1 + x2 + x3 + b.x;
    float sy = y0 + y1 + y2 + y3 + b.y;
    if (RELU) { sx = fmaxf(sx, 0.f); sy = fmaxf(sy, 0.f); }
    ((unsigned int*)outb)[(size_t)row * 64 + lane] =
        (unsigned int)f2bf(sx) | ((unsigned int)f2bf(sy) << 16);
}

// ---------------------------------------------------------------------------
// SpMM 64-wide (CSR, bf16 table): wave per row; half-waves take alternating
// edges; lane owns 2 feats (1 uint). Combine with shfl_xor(32); fp32 output.
// ---------------------------------------------------------------------------
__global__ __launch_bounds__(256) void spmm_gather64_out(
    const int* __restrict__ rp, const int* __restrict__ ccol,
    const float* __restrict__ cval, const unsigned short* __restrict__ y2b,
    const float* __restrict__ bias, float* __restrict__ out, int N)
{
    int row = (blockIdx.x * 256 + threadIdx.x) >> 6;
    if (row >= N) return;
    int lane = threadIdx.x & 63;
    int half = lane >> 5, fl = lane & 31;
    const unsigned int* xf = (const unsigned int*)y2b;

    int s = rp[row], e = rp[row + 1];
    float x0 = 0.f, y0 = 0.f, x1 = 0.f, y1 = 0.f;
    int i = s + half;
    for (; i + 2 < e; i += 4) {
        int   c0 = ccol[i],  c1 = ccol[i + 2];
        float v0 = cval[i],  v1 = cval[i + 2];
        unsigned int u0 = xf[(size_t)c0 * 32 + fl];
        unsigned int u1 = xf[(size_t)c1 * 32 + fl];
        x0 = fmaf(v0, bflo(u0), x0);  y0 = fmaf(v0, bfhi(u0), y0);
        x1 = fmaf(v1, bflo(u1), x1);  y1 = fmaf(v1, bfhi(u1), y1);
    }
    if (i < e) {
        int c0 = ccol[i]; float v0 = cval[i];
        unsigned int u0 = xf[(size_t)c0 * 32 + fl];
        x0 = fmaf(v0, bflo(u0), x0);  y0 = fmaf(v0, bfhi(u0), y0);
    }
    float sx = x0 + x1, sy = y0 + y1;
    sx += __shfl_xor(sx, 32);
    sy += __shfl_xor(sy, 32);
    if (half == 0) {
        float2 b = ((const float2*)bias)[fl];
        ((float2*)out)[(size_t)row * 32 + fl] =
            make_float2(sx + b.x, sy + b.y);
    }
}

extern "C" void kernel_launch(void* const* d_in, const int* in_sizes, int n_in,
                              void* d_out, int out_size, void* d_ws, size_t ws_size,
                              hipStream_t stream)
{
    const float* x    = (const float*)d_in[0];
    const int*   erow = (const int*)  d_in[1];
    const int*   ecol = (const int*)  d_in[2];
    const float* eval = (const float*)d_in[3];
    const float* W1   = (const float*)d_in[4];
    const float* b1   = (const float*)d_in[5];
    const float* W2   = (const float*)d_in[6];
    const float* b2   = (const float*)d_in[7];
    float*       out  = (float*)d_out;

    const int N = in_sizes[0] / 128;   // 100000
    const int E = in_sizes[1];         // 1600000
    const int NP = N + 64;             // pad so clamped OOB loads stay in-buffer

    // Workspace (~78 MB): bf16 tables first (16B-aligned strides), then ints.
    unsigned short* y1b = (unsigned short*)d_ws;          // [NP,128] bf16
    unsigned short* h2b = y1b + (size_t)NP * 128;         // [NP,128] bf16
    unsigned short* y2b = h2b + (size_t)NP * 128;         // [NP,64]  bf16
    unsigned short* W1t = y2b + (size_t)NP * 64;          // [128,128] bf16
    unsigned short* W2t = W1t + 128 * 128;                // [64,128]  bf16
    float* cval   = (float*)(W2t + 64 * 128);             // [E]
    int*   ccol   = (int*)(cval + E);                     // [E]
    int*   rp     = ccol + E;                             // [N+1]
    int*   cursor = rp + (N + 1);                         // [N]

    const int eblocks     = (E + 255) / 256;
    const int spmm_blocks = (N + 3) / 4;
    const int mfma_blocks = (N + 63) / 64;

    // ---- Build CSR (reused by both layers) ----
    hipMemsetAsync(cursor, 0, (size_t)N * sizeof(int), stream);
    hist_rows<<<eblocks, 256, 0, stream>>>(erow, cursor, E);
    scan_rowptr<<<1, 1024, 0, stream>>>(cursor, rp, N);
    hipMemcpyAsync(cursor, rp, (size_t)N * sizeof(int),
                   hipMemcpyDeviceToDevice, stream);
    fill_csr<<<eblocks, 256, 0, stream>>>(erow, ecol, eval, cursor,
                                          ccol, cval, E);

    // ---- Weights -> bf16, transposed to [OUT][128] ----
    cast_transpose_w<<<(128 * 128 + 255) / 256, 256, 0, stream>>>(W1, W1t, 128, 128);
    cast_transpose_w<<<(128 * 64 + 255) / 256, 256, 0, stream>>>(W2, W2t, 128, 64);

    // ---- Layer 1: y1b = bf16(x@W1) ; h2b = bf16(relu(A@y1b + b1)) ----
    gemm1_mfma<<<mfma_blocks, 256, 0, stream>>>(x, W1t, y1b, N);
    spmm_gather128<true><<<spmm_blocks, 256, 0, stream>>>(
        rp, ccol, cval, y1b, b1, h2b, N);

    // ---- Layer 2: y2b = bf16(h2b@W2) ; out = A@y2b + b2 ----
    gemm2_mfma<<<mfma_blocks, 256, 0, stream>>>(h2b, W2t, y2b, N);
    spmm_gather64_out<<<spmm_blocks, 256, 0, stream>>>(
        rp, ccol, cval, y2b, b2, out, N);
}

// Round 5
// 475.655 us; speedup vs baseline: 13.5529x; 1.2099x over previous
//
#include <hip/hip_runtime.h>

// GCN forward, reassociated + bf16 tables + MFMA GEMMs + packed CSR:
//   y1b = bf16(x @ W1)             (MFMA GEMM, fused into hist dispatch)
//   h2b = bf16(relu(A @ y1b + b1)) (SpMM 128-wide gather, bf16 table)
//   y2b = bf16(h2b @ W2)           (MFMA bf16 GEMM, N x 128 x 64)
//   out = A @ y2b + b2             (SpMM 64-wide gather, fp32 out)
// CSR built on device once per call: prep(zero+Wcast) -> hist(+gemm1) ->
// scan_partials -> scan_write(rp+cursor) -> fill (int2-packed edges).

typedef __attribute__((ext_vector_type(8))) short short8;
typedef __attribute__((ext_vector_type(4))) float floatx4;

#define SCH 2048   // elements per scan block (256 thr x 8)

static __device__ __forceinline__ unsigned short f2bf(float f) {
    unsigned int u = __builtin_bit_cast(unsigned int, f);
    u += 0x7fffu + ((u >> 16) & 1u);        // round-to-nearest-even
    return (unsigned short)(u >> 16);
}
static __device__ __forceinline__ float bflo(unsigned int u) {
    return __builtin_bit_cast(float, u << 16);
}
static __device__ __forceinline__ float bfhi(unsigned int u) {
    return __builtin_bit_cast(float, u & 0xffff0000u);
}

// ---------------------------------------------------------------------------
// Prep: zero deg[N]; W1[128,128] -> W1t[128][128] bf16; W2[128,64] -> W2t[64][128]
// ---------------------------------------------------------------------------
__global__ __launch_bounds__(256) void prep_kernel(
    const float* __restrict__ W1, const float* __restrict__ W2,
    unsigned short* __restrict__ W1t, unsigned short* __restrict__ W2t,
    int* __restrict__ deg, int N)
{
    int idx = blockIdx.x * 256 + threadIdx.x;
    if (idx < N) deg[idx] = 0;
    if (idx < 128 * 128) {
        int n = idx >> 7, k = idx & 127;
        W1t[idx] = f2bf(W1[(size_t)k * 128 + n]);
    }
    if (idx < 64 * 128) {
        int n = idx >> 7, k = idx & 127;
        W2t[idx] = f2bf(W2[(size_t)k * 64 + n]);
    }
}

// ---------------------------------------------------------------------------
// MFMA GEMM body: Y[N,OUT] = bf16(A[N,128] @ W), Wt is [OUT][128] bf16.
// Wave computes 16 rows x OUT cols via 16x16x32 MFMA.
// Verified gfx950 layouts: A/B frag [lane&15][quad*8+j]; C/D col=lane&15,
// row=quad*4+reg.
// ---------------------------------------------------------------------------
template<int OUT, bool AF32>
static __device__ __forceinline__ void gemm_mfma_body(
    const void* __restrict__ Av, const unsigned short* __restrict__ Wt,
    unsigned short* __restrict__ Y, int N, int bid)
{
    constexpr int NT = OUT / 16;
    const int lane = threadIdx.x & 63;
    const int wave = threadIdx.x >> 6;
    const int quad = lane >> 4;
    const int l16  = lane & 15;
    const int row0 = bid * 64 + wave * 16;
    int arow = row0 + l16;
    if (arow > N - 1) arow = N - 1;      // clamp: stores guarded below

    short8 af[4];
    if (AF32) {
        const float* ap = (const float*)Av + (size_t)arow * 128 + quad * 8;
        #pragma unroll
        for (int kt = 0; kt < 4; ++kt) {
            const float4* p = (const float4*)(ap + kt * 32);
            float4 lo = p[0], hi = p[1];
            short8 t;
            t[0] = (short)f2bf(lo.x); t[1] = (short)f2bf(lo.y);
            t[2] = (short)f2bf(lo.z); t[3] = (short)f2bf(lo.w);
            t[4] = (short)f2bf(hi.x); t[5] = (short)f2bf(hi.y);
            t[6] = (short)f2bf(hi.z); t[7] = (short)f2bf(hi.w);
            af[kt] = t;
        }
    } else {
        const unsigned short* ap =
            (const unsigned short*)Av + (size_t)arow * 128 + quad * 8;
        #pragma unroll
        for (int kt = 0; kt < 4; ++kt)
            af[kt] = *(const short8*)(ap + kt * 32);
    }

    floatx4 acc[NT];
    #pragma unroll
    for (int nt = 0; nt < NT; ++nt) acc[nt] = (floatx4){0.f, 0.f, 0.f, 0.f};

    #pragma unroll
    for (int nt = 0; nt < NT; ++nt) {
        const unsigned short* wp = Wt + (size_t)(nt * 16 + l16) * 128 + quad * 8;
        #pragma unroll
        for (int kt = 0; kt < 4; ++kt) {
            short8 bfr = *(const short8*)(wp + kt * 32);
            acc[nt] = __builtin_amdgcn_mfma_f32_16x16x32_bf16(
                af[kt], bfr, acc[nt], 0, 0, 0);
        }
    }

    #pragma unroll
    for (int nt = 0; nt < NT; ++nt) {
        int col = nt * 16 + l16;
        #pragma unroll
        for (int r = 0; r < 4; ++r) {
            int row = row0 + quad * 4 + r;
            if (row < N)
                Y[(size_t)row * OUT + col] = f2bf(acc[nt][r]);
        }
    }
}

// ---------------------------------------------------------------------------
// Fused: blocks [0,EB) do row histogram; blocks [EB,..) do gemm1 (x@W1 MFMA).
// gemm1's W1t comes from prep_kernel (previous dispatch) — cross-launch dep.
// ---------------------------------------------------------------------------
__global__ __launch_bounds__(256) void hist_gemm1_fused(
    const int* __restrict__ erow, int* __restrict__ deg, int E, int EB,
    const float* __restrict__ x, const unsigned short* __restrict__ W1t,
    unsigned short* __restrict__ y1b, int N)
{
    if ((int)blockIdx.x < EB) {
        int e = blockIdx.x * 256 + threadIdx.x;
        if (e < E) atomicAdd(&deg[erow[e]], 1);
    } else {
        gemm_mfma_body<128, true>(x, W1t, y1b, N, blockIdx.x - EB);
    }
}

// ---------------------------------------------------------------------------
// Scan phase A: per-block sums of deg chunks -> partial[blockIdx]
// ---------------------------------------------------------------------------
__global__ __launch_bounds__(256) void scan_partials(
    const int* __restrict__ deg, int* __restrict__ partial, int N)
{
    __shared__ int ws[4];
    int c0 = blockIdx.x * SCH + threadIdx.x * 8;
    int s = 0;
    if (c0 + 8 <= N) {
        int4 a = *(const int4*)(deg + c0);
        int4 b = *(const int4*)(deg + c0 + 4);
        s = a.x + a.y + a.z + a.w + b.x + b.y + b.z + b.w;
    } else {
        for (int j = 0; j < 8; ++j) { int i = c0 + j; if (i < N) s += deg[i]; }
    }
    #pragma unroll
    for (int d = 1; d < 64; d <<= 1) s += __shfl_xor(s, d);
    if ((threadIdx.x & 63) == 0) ws[threadIdx.x >> 6] = s;
    __syncthreads();
    if (threadIdx.x == 0)
        partial[blockIdx.x] = ws[0] + ws[1] + ws[2] + ws[3];
}

// ---------------------------------------------------------------------------
// Scan phase B: exclusive scan, writes rp[N+1] AND cursor[N] (copy of rp).
// Each block re-sums partial[0..bid) (NB <= 128 assumed; N <= 128*SCH).
// ---------------------------------------------------------------------------
__global__ __launch_bounds__(256) void scan_write(
    const int* __restrict__ deg, const int* __restrict__ partial,
    int* __restrict__ rp, int* __restrict__ cursor, int N, int E)
{
    __shared__ int sp[128];
    __shared__ int ws[4];
    const int tid = threadIdx.x, lane = tid & 63, wid = tid >> 6;
    const int bid = blockIdx.x, NB = gridDim.x;
    int c0 = bid * SCH + tid * 8;

    int d[8];
    if (c0 + 8 <= N) {
        int4 a = *(const int4*)(deg + c0);
        int4 b = *(const int4*)(deg + c0 + 4);
        d[0]=a.x; d[1]=a.y; d[2]=a.z; d[3]=a.w;
        d[4]=b.x; d[5]=b.y; d[6]=b.z; d[7]=b.w;
    } else {
        for (int j = 0; j < 8; ++j) { int i = c0 + j; d[j] = (i < N) ? deg[i] : 0; }
    }
    int s = d[0]+d[1]+d[2]+d[3]+d[4]+d[5]+d[6]+d[7];

    int sc = s;   // inclusive scan of per-thread sums within wave
    #pragma unroll
    for (int dd = 1; dd < 64; dd <<= 1) {
        int t = __shfl_up(sc, dd);
        if (lane >= dd) sc += t;
    }
    if (lane == 63) ws[wid] = sc;
    if (tid < NB) sp[tid] = partial[tid];
    __syncthreads();

    int woff = 0;
    for (int w = 0; w < wid; ++w) woff += ws[w];
    int bb = 0;
    for (int b = 0; b < bid; ++b) bb += sp[b];

    int run = bb + woff + (sc - s);   // exclusive prefix for this thread
    for (int j = 0; j < 8; ++j) {
        int i = c0 + j;
        if (i < N) { rp[i] = run; cursor[i] = run; run += d[j]; }
    }
    if (bid == 0 && tid == 0) rp[N] = E;
}

// ---------------------------------------------------------------------------
// CSR fill: one packed 8B scattered write per edge (halves dirty lines).
// ---------------------------------------------------------------------------
__global__ __launch_bounds__(256) void fill_csr_packed(
    const int* __restrict__ erow, const int* __restrict__ ecol,
    const float* __restrict__ eval, int* __restrict__ cursor,
    int2* __restrict__ edges, int E)
{
    int e = blockIdx.x * 256 + threadIdx.x;
    if (e < E) {
        int r = erow[e];
        int p = atomicAdd(&cursor[r], 1);
        edges[p] = make_int2(ecol[e], __float_as_int(eval[e]));
    }
}

// ---------------------------------------------------------------------------
// SpMM 128-wide (CSR, bf16 table): wave per row, lane owns 2 feats (1 uint).
// 4-edge unroll; fused bias+relu; bf16 output.
// ---------------------------------------------------------------------------
template<bool RELU>
__global__ __launch_bounds__(256) void spmm_gather128(
    const int* __restrict__ rp, const int2* __restrict__ edges,
    const unsigned short* __restrict__ xb,
    const float* __restrict__ bias, unsigned short* __restrict__ outb, int N)
{
    int row = (blockIdx.x * 256 + threadIdx.x) >> 6;
    if (row >= N) return;
    int lane = threadIdx.x & 63;
    const unsigned int* xf = (const unsigned int*)xb;

    int s = rp[row], e = rp[row + 1];
    float x0 = 0.f, y0 = 0.f, x1 = 0.f, y1 = 0.f;
    float x2 = 0.f, y2 = 0.f, x3 = 0.f, y3 = 0.f;
    int i = s;
    for (; i + 3 < e; i += 4) {
        int2 cv0 = edges[i],     cv1 = edges[i + 1];
        int2 cv2 = edges[i + 2], cv3 = edges[i + 3];
        unsigned int u0 = xf[(size_t)cv0.x * 64 + lane];
        unsigned int u1 = xf[(size_t)cv1.x * 64 + lane];
        unsigned int u2 = xf[(size_t)cv2.x * 64 + lane];
        unsigned int u3 = xf[(size_t)cv3.x * 64 + lane];
        float v0 = __int_as_float(cv0.y), v1 = __int_as_float(cv1.y);
        float v2 = __int_as_float(cv2.y), v3 = __int_as_float(cv3.y);
        x0 = fmaf(v0, bflo(u0), x0);  y0 = fmaf(v0, bfhi(u0), y0);
        x1 = fmaf(v1, bflo(u1), x1);  y1 = fmaf(v1, bfhi(u1), y1);
        x2 = fmaf(v2, bflo(u2), x2);  y2 = fmaf(v2, bfhi(u2), y2);
        x3 = fmaf(v3, bflo(u3), x3);  y3 = fmaf(v3, bfhi(u3), y3);
    }
    for (; i < e; ++i) {
        int2 cv = edges[i];
        float v0 = __int_as_float(cv.y);
        unsigned int u0 = xf[(size_t)cv.x * 64 + lane];
        x0 = fmaf(v0, bflo(u0), x0);  y0 = fmaf(v0, bfhi(u0), y0);
    }
    float2 b = ((const float2*)bias)[lane];
    float sx = x0 + x1 + x2 + x3 + b.x;
    float sy = y0 + y1 + y2 + y3 + b.y;
    if (RELU) { sx = fmaxf(sx, 0.f); sy = fmaxf(sy, 0.f); }
    ((unsigned int*)outb)[(size_t)row * 64 + lane] =
        (unsigned int)f2bf(sx) | ((unsigned int)f2bf(sy) << 16);
}

// ---------------------------------------------------------------------------
// SpMM 64-wide (CSR, bf16 table): wave per row; half-waves take alternating
// edges; lane owns 2 feats. Combine with shfl_xor(32); fp32 output + bias.
// ---------------------------------------------------------------------------
__global__ __launch_bounds__(256) void spmm_gather64_out(
    const int* __restrict__ rp, const int2* __restrict__ edges,
    const unsigned short* __restrict__ y2b,
    const float* __restrict__ bias, float* __restrict__ out, int N)
{
    int row = (blockIdx.x * 256 + threadIdx.x) >> 6;
    if (row >= N) return;
    int lane = threadIdx.x & 63;
    int half = lane >> 5, fl = lane & 31;
    const unsigned int* xf = (const unsigned int*)y2b;

    int s = rp[row], e = rp[row + 1];
    float x0 = 0.f, y0 = 0.f, x1 = 0.f, y1 = 0.f;
    int i = s + half;
    for (; i + 2 < e; i += 4) {
        int2 cv0 = edges[i], cv1 = edges[i + 2];
        unsigned int u0 = xf[(size_t)cv0.x * 32 + fl];
        unsigned int u1 = xf[(size_t)cv1.x * 32 + fl];
        float v0 = __int_as_float(cv0.y), v1 = __int_as_float(cv1.y);
        x0 = fmaf(v0, bflo(u0), x0);  y0 = fmaf(v0, bfhi(u0), y0);
        x1 = fmaf(v1, bflo(u1), x1);  y1 = fmaf(v1, bfhi(u1), y1);
    }
    if (i < e) {
        int2 cv = edges[i];
        float v0 = __int_as_float(cv.y);
        unsigned int u0 = xf[(size_t)cv.x * 32 + fl];
        x0 = fmaf(v0, bflo(u0), x0);  y0 = fmaf(v0, bfhi(u0), y0);
    }
    float sx = x0 + x1, sy = y0 + y1;
    sx += __shfl_xor(sx, 32);
    sy += __shfl_xor(sy, 32);
    if (half == 0) {
        float2 b = ((const float2*)bias)[fl];
        ((float2*)out)[(size_t)row * 32 + fl] =
            make_float2(sx + b.x, sy + b.y);
    }
}

__global__ __launch_bounds__(256) void gemm2_mfma(
    const unsigned short* __restrict__ A, const unsigned short* __restrict__ Wt,
    unsigned short* __restrict__ Y, int N)
{
    gemm_mfma_body<64, false>(A, Wt, Y, N, blockIdx.x);
}

extern "C" void kernel_launch(void* const* d_in, const int* in_sizes, int n_in,
                              void* d_out, int out_size, void* d_ws, size_t ws_size,
                              hipStream_t stream)
{
    const float* x    = (const float*)d_in[0];
    const int*   erow = (const int*)  d_in[1];
    const int*   ecol = (const int*)  d_in[2];
    const float* eval = (const float*)d_in[3];
    const float* W1   = (const float*)d_in[4];
    const float* b1   = (const float*)d_in[5];
    const float* W2   = (const float*)d_in[6];
    const float* b2   = (const float*)d_in[7];
    float*       out  = (float*)d_out;

    const int N = in_sizes[0] / 128;   // 100000
    const int E = in_sizes[1];         // 1600000
    const int NP = N + 64;             // pad so clamped loads stay in-buffer

    // Workspace (~78 MB)
    unsigned short* y1b = (unsigned short*)d_ws;          // [NP,128] bf16
    unsigned short* h2b = y1b + (size_t)NP * 128;         // [NP,128] bf16
    unsigned short* y2b = h2b + (size_t)NP * 128;         // [NP,64]  bf16
    unsigned short* W1t = y2b + (size_t)NP * 64;          // [128,128] bf16
    unsigned short* W2t = W1t + 128 * 128;                // [64,128]  bf16
    int2*  edges  = (int2*)(W2t + 64 * 128);              // [E] packed (c,v)
    int*   rp     = (int*)(edges + E);                    // [N+1]
    int*   cursor = rp + (N + 1);                         // [N]
    int*   deg    = cursor + N;                           // [N]
    int*   partial= deg + N;                              // [<=128]

    const int eblocks     = (E + 255) / 256;              // 6250
    const int spmm_blocks = (N + 3) / 4;
    const int mfma_blocks = (N + 63) / 64;                // 1563
    const int prep_blocks = (N + 255) / 256;
    const int scan_blocks = (N + SCH - 1) / SCH;          // 49 (<=128)

    // ---- Prep: zero deg, cast/transpose weights ----
    prep_kernel<<<prep_blocks, 256, 0, stream>>>(W1, W2, W1t, W2t, deg, N);

    // ---- Fused: histogram (blocks [0,eblocks)) + gemm1 y1b = bf16(x@W1) ----
    hist_gemm1_fused<<<eblocks + mfma_blocks, 256, 0, stream>>>(
        erow, deg, E, eblocks, x, W1t, y1b, N);

    // ---- Exclusive scan deg -> rp (and cursor) ----
    scan_partials<<<scan_blocks, 256, 0, stream>>>(deg, partial, N);
    scan_write<<<scan_blocks, 256, 0, stream>>>(deg, partial, rp, cursor, N, E);

    // ---- CSR fill (packed 8B per edge) ----
    fill_csr_packed<<<eblocks, 256, 0, stream>>>(erow, ecol, eval, cursor,
                                                 edges, E);

    // ---- Layer 1 SpMM: h2b = bf16(relu(A@y1b + b1)) ----
    spmm_gather128<true><<<spmm_blocks, 256, 0, stream>>>(
        rp, edges, y1b, b1, h2b, N);

    // ---- Layer 2: y2b = bf16(h2b@W2) ; out = A@y2b + b2 ----
    gemm2_mfma<<<mfma_blocks, 256, 0, stream>>>(h2b, W2t, y2b, N);
    spmm_gather64_out<<<spmm_blocks, 256, 0, stream>>>(
        rp, edges, y2b, b2, out, N);
}

// Round 6
// 408.131 us; speedup vs baseline: 15.7951x; 1.1654x over previous
//
#include <hip/hip_runtime.h>

// GCN forward, reassociated + bf16 tables + MFMA GEMMs + rank-based CSR:
//   y1b = bf16(x @ W1)             (MFMA GEMM, fused into hist dispatch)
//   h2b = bf16(relu(A @ y1b + b1)) (SpMM 128-wide gather, bf16 table)
//   y2b = bf16(h2b @ W2)           (MFMA bf16 GEMM)
//   out = A @ y2b + b2             (SpMM 64-wide gather, fp32 out)
// CSR build: prep(zero+Wcast) -> hist(rank[e]=atomicAdd)+gemm1 ->
// scan_partials -> scan_write(rp) -> fill (atomic-free, XCD-range-filtered).

typedef __attribute__((ext_vector_type(8))) short short8;
typedef __attribute__((ext_vector_type(4))) float floatx4;

#define SCH 2048   // elements per scan block (256 thr x 8)

static __device__ __forceinline__ unsigned short f2bf(float f) {
    unsigned int u = __builtin_bit_cast(unsigned int, f);
    u += 0x7fffu + ((u >> 16) & 1u);        // round-to-nearest-even
    return (unsigned short)(u >> 16);
}
static __device__ __forceinline__ float bflo(unsigned int u) {
    return __builtin_bit_cast(float, u << 16);
}
static __device__ __forceinline__ float bfhi(unsigned int u) {
    return __builtin_bit_cast(float, u & 0xffff0000u);
}

// ---------------------------------------------------------------------------
// Prep: zero deg[N]; W1[128,128] -> W1t[128][128] bf16; W2[128,64] -> W2t[64][128]
// ---------------------------------------------------------------------------
__global__ __launch_bounds__(256) void prep_kernel(
    const float* __restrict__ W1, const float* __restrict__ W2,
    unsigned short* __restrict__ W1t, unsigned short* __restrict__ W2t,
    int* __restrict__ deg, int N)
{
    int idx = blockIdx.x * 256 + threadIdx.x;
    if (idx < N) deg[idx] = 0;
    if (idx < 128 * 128) {
        int n = idx >> 7, k = idx & 127;
        W1t[idx] = f2bf(W1[(size_t)k * 128 + n]);
    }
    if (idx < 64 * 128) {
        int n = idx >> 7, k = idx & 127;
        W2t[idx] = f2bf(W2[(size_t)k * 64 + n]);
    }
}

// ---------------------------------------------------------------------------
// MFMA GEMM body: Y[N,OUT] = bf16(A[N,128] @ W), Wt is [OUT][128] bf16.
// Verified gfx950 layouts: A/B frag [lane&15][quad*8+j]; C/D col=lane&15,
// row=quad*4+reg.
// ---------------------------------------------------------------------------
template<int OUT, bool AF32>
static __device__ __forceinline__ void gemm_mfma_body(
    const void* __restrict__ Av, const unsigned short* __restrict__ Wt,
    unsigned short* __restrict__ Y, int N, int bid)
{
    constexpr int NT = OUT / 16;
    const int lane = threadIdx.x & 63;
    const int wave = threadIdx.x >> 6;
    const int quad = lane >> 4;
    const int l16  = lane & 15;
    const int row0 = bid * 64 + wave * 16;
    int arow = row0 + l16;
    if (arow > N - 1) arow = N - 1;      // clamp: stores guarded below

    short8 af[4];
    if (AF32) {
        const float* ap = (const float*)Av + (size_t)arow * 128 + quad * 8;
        #pragma unroll
        for (int kt = 0; kt < 4; ++kt) {
            const float4* p = (const float4*)(ap + kt * 32);
            float4 lo = p[0], hi = p[1];
            short8 t;
            t[0] = (short)f2bf(lo.x); t[1] = (short)f2bf(lo.y);
            t[2] = (short)f2bf(lo.z); t[3] = (short)f2bf(lo.w);
            t[4] = (short)f2bf(hi.x); t[5] = (short)f2bf(hi.y);
            t[6] = (short)f2bf(hi.z); t[7] = (short)f2bf(hi.w);
            af[kt] = t;
        }
    } else {
        const unsigned short* ap =
            (const unsigned short*)Av + (size_t)arow * 128 + quad * 8;
        #pragma unroll
        for (int kt = 0; kt < 4; ++kt)
            af[kt] = *(const short8*)(ap + kt * 32);
    }

    floatx4 acc[NT];
    #pragma unroll
    for (int nt = 0; nt < NT; ++nt) acc[nt] = (floatx4){0.f, 0.f, 0.f, 0.f};

    #pragma unroll
    for (int nt = 0; nt < NT; ++nt) {
        const unsigned short* wp = Wt + (size_t)(nt * 16 + l16) * 128 + quad * 8;
        #pragma unroll
        for (int kt = 0; kt < 4; ++kt) {
            short8 bfr = *(const short8*)(wp + kt * 32);
            acc[nt] = __builtin_amdgcn_mfma_f32_16x16x32_bf16(
                af[kt], bfr, acc[nt], 0, 0, 0);
        }
    }

    #pragma unroll
    for (int nt = 0; nt < NT; ++nt) {
        int col = nt * 16 + l16;
        #pragma unroll
        for (int r = 0; r < 4; ++r) {
            int row = row0 + quad * 4 + r;
            if (row < N)
                Y[(size_t)row * OUT + col] = f2bf(acc[nt][r]);
        }
    }
}

// ---------------------------------------------------------------------------
// Fused: blocks [0,EB) do histogram AND record rank[e] (= atomicAdd return);
// blocks [EB,..) do gemm1 (x@W1 MFMA). W1t from prep_kernel (prior dispatch).
// ---------------------------------------------------------------------------
__global__ __launch_bounds__(256) void hist_gemm1_fused(
    const int* __restrict__ erow, int* __restrict__ deg,
    int* __restrict__ rank, int E, int EB,
    const float* __restrict__ x, const unsigned short* __restrict__ W1t,
    unsigned short* __restrict__ y1b, int N)
{
    if ((int)blockIdx.x < EB) {
        int e = blockIdx.x * 256 + threadIdx.x;
        if (e < E) rank[e] = atomicAdd(&deg[erow[e]], 1);
    } else {
        gemm_mfma_body<128, true>(x, W1t, y1b, N, blockIdx.x - EB);
    }
}

// ---------------------------------------------------------------------------
// Scan phase A: per-block sums of deg chunks -> partial[blockIdx]
// ---------------------------------------------------------------------------
__global__ __launch_bounds__(256) void scan_partials(
    const int* __restrict__ deg, int* __restrict__ partial, int N)
{
    __shared__ int ws[4];
    int c0 = blockIdx.x * SCH + threadIdx.x * 8;
    int s = 0;
    if (c0 + 8 <= N) {
        int4 a = *(const int4*)(deg + c0);
        int4 b = *(const int4*)(deg + c0 + 4);
        s = a.x + a.y + a.z + a.w + b.x + b.y + b.z + b.w;
    } else {
        for (int j = 0; j < 8; ++j) { int i = c0 + j; if (i < N) s += deg[i]; }
    }
    #pragma unroll
    for (int d = 1; d < 64; d <<= 1) s += __shfl_xor(s, d);
    if ((threadIdx.x & 63) == 0) ws[threadIdx.x >> 6] = s;
    __syncthreads();
    if (threadIdx.x == 0)
        partial[blockIdx.x] = ws[0] + ws[1] + ws[2] + ws[3];
}

// ---------------------------------------------------------------------------
// Scan phase B: exclusive scan deg -> rp[N+1].
// ---------------------------------------------------------------------------
__global__ __launch_bounds__(256) void scan_write(
    const int* __restrict__ deg, const int* __restrict__ partial,
    int* __restrict__ rp, int N, int E)
{
    __shared__ int sp[128];
    __shared__ int ws[4];
    const int tid = threadIdx.x, lane = tid & 63, wid = tid >> 6;
    const int bid = blockIdx.x, NB = gridDim.x;
    int c0 = bid * SCH + tid * 8;

    int d[8];
    if (c0 + 8 <= N) {
        int4 a = *(const int4*)(deg + c0);
        int4 b = *(const int4*)(deg + c0 + 4);
        d[0]=a.x; d[1]=a.y; d[2]=a.z; d[3]=a.w;
        d[4]=b.x; d[5]=b.y; d[6]=b.z; d[7]=b.w;
    } else {
        for (int j = 0; j < 8; ++j) { int i = c0 + j; d[j] = (i < N) ? deg[i] : 0; }
    }
    int s = d[0]+d[1]+d[2]+d[3]+d[4]+d[5]+d[6]+d[7];

    int sc = s;
    #pragma unroll
    for (int dd = 1; dd < 64; dd <<= 1) {
        int t = __shfl_up(sc, dd);
        if (lane >= dd) sc += t;
    }
    if (lane == 63) ws[wid] = sc;
    if (tid < NB) sp[tid] = partial[tid];
    __syncthreads();

    int woff = 0;
    for (int w = 0; w < wid; ++w) woff += ws[w];
    int bb = 0;
    for (int b = 0; b < bid; ++b) bb += sp[b];

    int run = bb + woff + (sc - s);
    for (int j = 0; j < 8; ++j) {
        int i = c0 + j;
        if (i < N) { rp[i] = run; run += d[j]; }
    }
    if (bid == 0 && tid == 0) rp[N] = E;
}

// ---------------------------------------------------------------------------
// CSR fill, atomic-free + XCD-range-filtered.
// Grid = 8 * CB. Block handles range g = blockIdx&7 (rows [g*RSTEP,(g+1)*RSTEP)),
// chunk = blockIdx>>3 of 1024 edges. Under round-robin workgroup->XCD dispatch
// all blocks of one range land on one XCD, so the range's ~1.6 MB slice of
// `edges` stays in that XCD's L2 and scattered 8B writes MERGE before
// writeback. 8x streaming re-read of edge arrays is the price (cheap).
// p = rp[r] + rank[e]  (no atomics).
// ---------------------------------------------------------------------------
__global__ __launch_bounds__(256) void fill_csr_xcd(
    const int* __restrict__ erow, const int* __restrict__ ecol,
    const float* __restrict__ eval, const int* __restrict__ rank,
    const int* __restrict__ rp, int2* __restrict__ edges,
    int E, int RSTEP, int N)
{
    const int g     = blockIdx.x & 7;
    const int chunk = blockIdx.x >> 3;
    const int lo = g * RSTEP;
    const int hi = min(lo + RSTEP, N);
    int base = chunk * 1024 + (int)threadIdx.x * 4;
    if (base >= E) return;

    if (base + 4 <= E) {
        int4   r4 = *(const int4*)(erow + base);
        int4   k4 = *(const int4*)(rank + base);
        int4   c4 = *(const int4*)(ecol + base);
        float4 v4 = *(const float4*)(eval + base);
        int   rr[4] = {r4.x, r4.y, r4.z, r4.w};
        int   kk[4] = {k4.x, k4.y, k4.z, k4.w};
        int   cc[4] = {c4.x, c4.y, c4.z, c4.w};
        float vv[4] = {v4.x, v4.y, v4.z, v4.w};
        #pragma unroll
        for (int j = 0; j < 4; ++j) {
            int r = rr[j];
            if (r >= lo && r < hi)
                edges[rp[r] + kk[j]] = make_int2(cc[j], __float_as_int(vv[j]));
        }
    } else {
        for (int j = 0; j < 4; ++j) {
            int e = base + j;
            if (e < E) {
                int r = erow[e];
                if (r >= lo && r < hi)
                    edges[rp[r] + rank[e]] =
                        make_int2(ecol[e], __float_as_int(eval[e]));
            }
        }
    }
}

// ---------------------------------------------------------------------------
// SpMM 128-wide (CSR, bf16 table): wave per row, lane owns 2 feats (1 uint).
// 4-edge unroll; fused bias+relu; bf16 output.
// ---------------------------------------------------------------------------
template<bool RELU>
__global__ __launch_bounds__(256) void spmm_gather128(
    const int* __restrict__ rp, const int2* __restrict__ edges,
    const unsigned short* __restrict__ xb,
    const float* __restrict__ bias, unsigned short* __restrict__ outb, int N)
{
    int row = (blockIdx.x * 256 + threadIdx.x) >> 6;
    if (row >= N) return;
    int lane = threadIdx.x & 63;
    const unsigned int* xf = (const unsigned int*)xb;

    int s = rp[row], e = rp[row + 1];
    float x0 = 0.f, y0 = 0.f, x1 = 0.f, y1 = 0.f;
    float x2 = 0.f, y2 = 0.f, x3 = 0.f, y3 = 0.f;
    int i = s;
    for (; i + 3 < e; i += 4) {
        int2 cv0 = edges[i],     cv1 = edges[i + 1];
        int2 cv2 = edges[i + 2], cv3 = edges[i + 3];
        unsigned int u0 = xf[(size_t)cv0.x * 64 + lane];
        unsigned int u1 = xf[(size_t)cv1.x * 64 + lane];
        unsigned int u2 = xf[(size_t)cv2.x * 64 + lane];
        unsigned int u3 = xf[(size_t)cv3.x * 64 + lane];
        float v0 = __int_as_float(cv0.y), v1 = __int_as_float(cv1.y);
        float v2 = __int_as_float(cv2.y), v3 = __int_as_float(cv3.y);
        x0 = fmaf(v0, bflo(u0), x0);  y0 = fmaf(v0, bfhi(u0), y0);
        x1 = fmaf(v1, bflo(u1), x1);  y1 = fmaf(v1, bfhi(u1), y1);
        x2 = fmaf(v2, bflo(u2), x2);  y2 = fmaf(v2, bfhi(u2), y2);
        x3 = fmaf(v3, bflo(u3), x3);  y3 = fmaf(v3, bfhi(u3), y3);
    }
    for (; i < e; ++i) {
        int2 cv = edges[i];
        float v0 = __int_as_float(cv.y);
        unsigned int u0 = xf[(size_t)cv.x * 64 + lane];
        x0 = fmaf(v0, bflo(u0), x0);  y0 = fmaf(v0, bfhi(u0), y0);
    }
    float2 b = ((const float2*)bias)[lane];
    float sx = x0 + x1 + x2 + x3 + b.x;
    float sy = y0 + y1 + y2 + y3 + b.y;
    if (RELU) { sx = fmaxf(sx, 0.f); sy = fmaxf(sy, 0.f); }
    ((unsigned int*)outb)[(size_t)row * 64 + lane] =
        (unsigned int)f2bf(sx) | ((unsigned int)f2bf(sy) << 16);
}

// ---------------------------------------------------------------------------
// SpMM 64-wide (CSR, bf16 table): wave per row; half-waves take alternating
// edges; lane owns 2 feats. Combine with shfl_xor(32); fp32 output + bias.
// ---------------------------------------------------------------------------
__global__ __launch_bounds__(256) void spmm_gather64_out(
    const int* __restrict__ rp, const int2* __restrict__ edges,
    const unsigned short* __restrict__ y2b,
    const float* __restrict__ bias, float* __restrict__ out, int N)
{
    int row = (blockIdx.x * 256 + threadIdx.x) >> 6;
    if (row >= N) return;
    int lane = threadIdx.x & 63;
    int half = lane >> 5, fl = lane & 31;
    const unsigned int* xf = (const unsigned int*)y2b;

    int s = rp[row], e = rp[row + 1];
    float x0 = 0.f, y0 = 0.f, x1 = 0.f, y1 = 0.f;
    int i = s + half;
    for (; i + 2 < e; i += 4) {
        int2 cv0 = edges[i], cv1 = edges[i + 2];
        unsigned int u0 = xf[(size_t)cv0.x * 32 + fl];
        unsigned int u1 = xf[(size_t)cv1.x * 32 + fl];
        float v0 = __int_as_float(cv0.y), v1 = __int_as_float(cv1.y);
        x0 = fmaf(v0, bflo(u0), x0);  y0 = fmaf(v0, bfhi(u0), y0);
        x1 = fmaf(v1, bflo(u1), x1);  y1 = fmaf(v1, bfhi(u1), y1);
    }
    if (i < e) {
        int2 cv = edges[i];
        float v0 = __int_as_float(cv.y);
        unsigned int u0 = xf[(size_t)cv.x * 32 + fl];
        x0 = fmaf(v0, bflo(u0), x0);  y0 = fmaf(v0, bfhi(u0), y0);
    }
    float sx = x0 + x1, sy = y0 + y1;
    sx += __shfl_xor(sx, 32);
    sy += __shfl_xor(sy, 32);
    if (half == 0) {
        float2 b = ((const float2*)bias)[fl];
        ((float2*)out)[(size_t)row * 32 + fl] =
            make_float2(sx + b.x, sy + b.y);
    }
}

__global__ __launch_bounds__(256) void gemm2_mfma(
    const unsigned short* __restrict__ A, const unsigned short* __restrict__ Wt,
    unsigned short* __restrict__ Y, int N)
{
    gemm_mfma_body<64, false>(A, Wt, Y, N, blockIdx.x);
}

extern "C" void kernel_launch(void* const* d_in, const int* in_sizes, int n_in,
                              void* d_out, int out_size, void* d_ws, size_t ws_size,
                              hipStream_t stream)
{
    const float* x    = (const float*)d_in[0];
    const int*   erow = (const int*)  d_in[1];
    const int*   ecol = (const int*)  d_in[2];
    const float* eval = (const float*)d_in[3];
    const float* W1   = (const float*)d_in[4];
    const float* b1   = (const float*)d_in[5];
    const float* W2   = (const float*)d_in[6];
    const float* b2   = (const float*)d_in[7];
    float*       out  = (float*)d_out;

    const int N = in_sizes[0] / 128;   // 100000
    const int E = in_sizes[1];         // 1600000
    const int NP = N + 64;             // pad so clamped loads stay in-buffer

    // Workspace (~84 MB)
    unsigned short* y1b = (unsigned short*)d_ws;          // [NP,128] bf16
    unsigned short* h2b = y1b + (size_t)NP * 128;         // [NP,128] bf16
    unsigned short* y2b = h2b + (size_t)NP * 128;         // [NP,64]  bf16
    unsigned short* W1t = y2b + (size_t)NP * 64;          // [128,128] bf16
    unsigned short* W2t = W1t + 128 * 128;                // [64,128]  bf16
    int2*  edges  = (int2*)(W2t + 64 * 128);              // [E] packed (c,v)
    int*   rank   = (int*)(edges + E);                    // [E]
    int*   rp     = rank + E;                             // [N+1]
    int*   deg    = rp + (N + 1);                         // [N]
    int*   partial= deg + N;                              // [<=128]

    const int eblocks     = (E + 255) / 256;              // 6250
    const int spmm_blocks = (N + 3) / 4;
    const int mfma_blocks = (N + 63) / 64;                // 1563
    const int prep_blocks = (N + 255) / 256;
    const int scan_blocks = (N + SCH - 1) / SCH;          // 49 (<=128)
    const int RSTEP       = (N + 7) / 8;                  // rows per XCD range
    const int fill_chunks = (E + 1023) / 1024;            // 1563
    const int fill_blocks = 8 * fill_chunks;

    // ---- Prep: zero deg, cast/transpose weights ----
    prep_kernel<<<prep_blocks, 256, 0, stream>>>(W1, W2, W1t, W2t, deg, N);

    // ---- Fused: histogram+rank (blocks [0,eblocks)) + gemm1 y1b=bf16(x@W1) ----
    hist_gemm1_fused<<<eblocks + mfma_blocks, 256, 0, stream>>>(
        erow, deg, rank, E, eblocks, x, W1t, y1b, N);

    // ---- Exclusive scan deg -> rp ----
    scan_partials<<<scan_blocks, 256, 0, stream>>>(deg, partial, N);
    scan_write<<<scan_blocks, 256, 0, stream>>>(deg, partial, rp, N, E);

    // ---- CSR fill: atomic-free, XCD-range-filtered scatter ----
    fill_csr_xcd<<<fill_blocks, 256, 0, stream>>>(
        erow, ecol, eval, rank, rp, edges, E, RSTEP, N);

    // ---- Layer 1 SpMM: h2b = bf16(relu(A@y1b + b1)) ----
    spmm_gather128<true><<<spmm_blocks, 256, 0, stream>>>(
        rp, edges, y1b, b1, h2b, N);

    // ---- Layer 2: y2b = bf16(h2b@W2) ; out = A@y2b + b2 ----
    gemm2_mfma<<<mfma_blocks, 256, 0, stream>>>(h2b, W2t, y2b, N);
    spmm_gather64_out<<<spmm_blocks, 256, 0, stream>>>(
        rp, edges, y2b, b2, out, N);
}